// Round 9
// baseline (1203.830 us; speedup 1.0000x reference)
//
#include <hip/hip_runtime.h>
#include <hip/hip_fp16.h>
#include <math.h>

// Problem constants
#define H_IN   256
#define W_IN   256
#define CIN    3
#define COUT   128
#define NB     8
#define KS     3
#define H_OUT  254
#define W_OUT  254
#define ROW_F  (W_IN * CIN)          // 768 floats per input row

#define SIG_OFF  ((size_t)NB * H_OUT * W_OUT * COUT)   // 66,064,384 floats
#define TOTAL_F  (2 * SIG_OFF)                          // 132,128,768 floats
#define OUT_BYTES ((size_t)TOTAL_F * 4)                 // 528,515,072 B
#define PASSES 5

typedef float f32x4 __attribute__((ext_vector_type(4)));

// v_fma_mix_f32: acc(f32) += f16(half of wpk) * x(f32)
#define FMA_MIX_LO(acc, wp, xv) \
    asm("v_fma_mix_f32 %0, %1, %2, %0 op_sel:[0,0,0] op_sel_hi:[1,0,0]" \
        : "+v"(acc) : "v"(wp), "v"(xv))
#define FMA_MIX_HI(acc, wp, xv) \
    asm("v_fma_mix_f32 %0, %1, %2, %0 op_sel:[1,0,0] op_sel_hi:[1,0,0]" \
        : "+v"(acc) : "v"(wp), "v"(xv))

// ---------------- Real kernel: bit-identical to R2 (114.5 us best) ---------
__global__ __launch_bounds__(256, 4)
void conv_meanvar_kernel(const float* __restrict__ in,
                         const float* __restrict__ w_mu,
                         const float* __restrict__ w_sigma,
                         float* __restrict__ out)
{
    __shared__ float lds[3 * ROW_F + 32];

    const int h   = blockIdx.x;
    const int n   = blockIdx.y;
    const int tid = threadIdx.x;
    const int px  = tid >> 5;
    const int c4  = (tid & 31) * 4;

    const float* src = in + (size_t)(n * H_IN + h) * ROW_F;
    if (tid < 144) {
        const f32x4* s4 = reinterpret_cast<const f32x4*>(src) + tid * 4;
        f32x4* d4 = reinterpret_cast<f32x4*>(lds) + tid * 4;
        d4[0] = s4[0]; d4[1] = s4[1]; d4[2] = s4[2]; d4[3] = s4[3];
    }

    unsigned int wpk[27][2];
    #pragma unroll
    for (int kk = 0; kk < 27; ++kk) {
        f32x4 w = *reinterpret_cast<const f32x4*>(w_mu + kk * COUT + c4);
        wpk[kk][0] = (unsigned int)__half_as_ushort(__float2half(w.x))
                   | ((unsigned int)__half_as_ushort(__float2half(w.y)) << 16);
        wpk[kk][1] = (unsigned int)__half_as_ushort(__float2half(w.z))
                   | ((unsigned int)__half_as_ushort(__float2half(w.w)) << 16);
    }

    f32x4 ws = *reinterpret_cast<const f32x4*>(w_sigma + c4);
    float sp[4];
    sp[0] = log1pf(expf(ws.x));
    sp[1] = log1pf(expf(ws.y));
    sp[2] = log1pf(expf(ws.z));
    sp[3] = log1pf(expf(ws.w));

    __syncthreads();

    const size_t pix_base = (size_t)(n * H_OUT + h) * W_OUT;
    float* const out_sig  = out + SIG_OFF;

    #pragma unroll 1
    for (int it = 0; it < 8; ++it) {
        const int p0 = it * 32 + px * 4;

        float mu[4][4];
        float ss[4];
        #pragma unroll
        for (int j = 0; j < 4; ++j) {
            ss[j] = 0.f;
            mu[j][0] = mu[j][1] = mu[j][2] = mu[j][3] = 0.f;
        }

        #pragma unroll
        for (int kh = 0; kh < KS; ++kh) {
            const f32x4* rq = reinterpret_cast<const f32x4*>(
                                  &lds[kh * ROW_F + p0 * 3]);
            float r[20];
            *reinterpret_cast<f32x4*>(&r[0])  = rq[0];
            *reinterpret_cast<f32x4*>(&r[4])  = rq[1];
            *reinterpret_cast<f32x4*>(&r[8])  = rq[2];
            *reinterpret_cast<f32x4*>(&r[12]) = rq[3];
            *reinterpret_cast<f32x4*>(&r[16]) = rq[4];

            #pragma unroll
            for (int j = 0; j < 4; ++j) {
                #pragma unroll
                for (int q = 0; q < 9; ++q) {
                    const float x = r[j * 3 + q];
                    const int kk = kh * 9 + q;
                    FMA_MIX_LO(mu[j][0], wpk[kk][0], x);
                    FMA_MIX_HI(mu[j][1], wpk[kk][0], x);
                    FMA_MIX_LO(mu[j][2], wpk[kk][1], x);
                    FMA_MIX_HI(mu[j][3], wpk[kk][1], x);
                    ss[j] = fmaf(x, x, ss[j]);
                }
            }
        }

        #pragma unroll
        for (int j = 0; j < 4; ++j) {
            const int p = p0 + j;
            if (p < W_OUT) {
                const size_t o = (pix_base + p) * COUT + c4;
                f32x4 m = {mu[j][0], mu[j][1], mu[j][2], mu[j][3]};
                *reinterpret_cast<f32x4*>(out + o) = m;
                f32x4 sg = {ss[j] * sp[0], ss[j] * sp[1],
                            ss[j] * sp[2], ss[j] * sp[3]};
                *reinterpret_cast<f32x4*>(out + SIG_OFF + o) = sg;
            }
        }
    }
}

// ---------------- Probe 1: exact conv store pattern, stores only ------------
__global__ __launch_bounds__(256, 4)
void probe_conv_pattern(float* __restrict__ ws)
{
    const int h   = blockIdx.x;
    const int n   = blockIdx.y;
    const int tid = threadIdx.x;
    const int px  = tid >> 5;
    const int c4  = (tid & 31) * 4;
    const size_t pix_base = (size_t)(n * H_OUT + h) * W_OUT;

    for (int k = 0; k < PASSES; ++k) {
        const float v = (float)(k + tid);
        #pragma unroll 1
        for (int it = 0; it < 8; ++it) {
            const int p0 = it * 32 + px * 4;
            #pragma unroll
            for (int j = 0; j < 4; ++j) {
                const int p = p0 + j;
                if (p < W_OUT) {
                    const size_t o = (pix_base + p) * COUT + c4;
                    f32x4 m = {v, v + 1.f, v + 2.f, v + 3.f};
                    *reinterpret_cast<f32x4*>(ws + o) = m;
                    *reinterpret_cast<f32x4*>(ws + SIG_OFF + o) = m;
                }
            }
        }
        __asm__ __volatile__("" ::: "memory");   // forbid cross-pass DSE
    }
}

// ---------------- Probe 2: per-block contiguous chunk, single stream --------
__global__ __launch_bounds__(256, 4)
void probe_block_chunk(float* __restrict__ ws)
{
    const size_t NV4   = TOTAL_F / 4;                    // 33,032,192 vec4
    const size_t CHUNK = (NV4 + 2031) / 2032;            // 16,257 vec4/block
    const size_t b     = blockIdx.x;
    const size_t lo    = b * CHUNK;
    const size_t hi    = (lo + CHUNK < NV4) ? lo + CHUNK : NV4;
    f32x4* w4 = reinterpret_cast<f32x4*>(ws);

    for (int k = 0; k < PASSES; ++k) {
        const float v = (float)(k + threadIdx.x);
        f32x4 m = {v, v + 1.f, v + 2.f, v + 3.f};
        for (size_t i = lo + threadIdx.x; i < hi; i += 256)
            w4[i] = m;
        __asm__ __volatile__("" ::: "memory");
    }
}

// ---------------- Probe 3: flat grid-stride, fill-style ---------------------
__global__ __launch_bounds__(256, 4)
void probe_grid_stride(float* __restrict__ ws)
{
    const size_t NV4 = TOTAL_F / 4;
    f32x4* w4 = reinterpret_cast<f32x4*>(ws);
    const size_t step = (size_t)gridDim.x * 256;

    for (int k = 0; k < PASSES; ++k) {
        const float v = (float)(k + threadIdx.x);
        f32x4 m = {v, v + 1.f, v + 2.f, v + 3.f};
        for (size_t i = (size_t)blockIdx.x * 256 + threadIdx.x; i < NV4; i += step)
            w4[i] = m;
        __asm__ __volatile__("" ::: "memory");
    }
}

extern "C" void kernel_launch(void* const* d_in, const int* in_sizes, int n_in,
                              void* d_out, int out_size, void* d_ws, size_t ws_size,
                              hipStream_t stream)
{
    const float* in      = (const float*)d_in[0];
    const float* w_mu    = (const float*)d_in[1];
    const float* w_sigma = (const float*)d_in[2];
    float* out           = (float*)d_out;

    dim3 grid(H_OUT, NB);
    dim3 block(256);
    conv_meanvar_kernel<<<grid, block, 0, stream>>>(in, w_mu, w_sigma, out);

    // --- diagnostic probes into scratch (skipped if ws too small) ---
    if (ws_size >= OUT_BYTES) {
        float* wsf = (float*)d_ws;
        probe_conv_pattern<<<grid, block, 0, stream>>>(wsf);
        probe_block_chunk<<<dim3(2032), block, 0, stream>>>(wsf);
        probe_grid_stride<<<dim3(2032), block, 0, stream>>>(wsf);
    }
}

// Round 10
// 513.923 us; speedup vs baseline: 2.3424x; 2.3424x over previous
//
#include <hip/hip_runtime.h>
#include <hip/hip_fp16.h>
#include <math.h>

// Problem constants
#define H_IN   256
#define W_IN   256
#define CIN    3
#define COUT   128
#define NB     8
#define KS     3
#define H_OUT  254
#define W_OUT  254
#define ROW_F  (W_IN * CIN)          // 768 floats per input row
#define PASSES 5                     // diagnostic: 5x work to surface in rocprof top-5

typedef float f32x4 __attribute__((ext_vector_type(4)));

// v_fma_mix_f32: acc(f32) += f16(half of wpk) * x(f32)
#define FMA_MIX_LO(acc, wp, xv) \
    asm("v_fma_mix_f32 %0, %1, %2, %0 op_sel:[0,0,0] op_sel_hi:[1,0,0]" \
        : "+v"(acc) : "v"(wp), "v"(xv))
#define FMA_MIX_HI(acc, wp, xv) \
    asm("v_fma_mix_f32 %0, %1, %2, %0 op_sel:[1,0,0] op_sel_hi:[1,0,0]" \
        : "+v"(acc) : "v"(wp), "v"(xv))

__global__ __launch_bounds__(256, 4)
void conv_meanvar_kernel(const float* __restrict__ in,
                         const float* __restrict__ w_mu,
                         const float* __restrict__ w_sigma,
                         float* __restrict__ out)
{
    __shared__ float lds[3 * ROW_F + 32];

    const int h   = blockIdx.x;
    const int n   = blockIdx.y;
    const int tid = threadIdx.x;
    const int px  = tid >> 5;
    const int c4  = (tid & 31) * 4;

    const float* src = in + (size_t)(n * H_IN + h) * ROW_F;
    if (tid < 144) {
        const f32x4* s4 = reinterpret_cast<const f32x4*>(src) + tid * 4;
        f32x4* d4 = reinterpret_cast<f32x4*>(lds) + tid * 4;
        d4[0] = s4[0]; d4[1] = s4[1]; d4[2] = s4[2]; d4[3] = s4[3];
    }

    unsigned int wpk[27][2];
    #pragma unroll
    for (int kk = 0; kk < 27; ++kk) {
        f32x4 w = *reinterpret_cast<const f32x4*>(w_mu + kk * COUT + c4);
        wpk[kk][0] = (unsigned int)__half_as_ushort(__float2half(w.x))
                   | ((unsigned int)__half_as_ushort(__float2half(w.y)) << 16);
        wpk[kk][1] = (unsigned int)__half_as_ushort(__float2half(w.z))
                   | ((unsigned int)__half_as_ushort(__float2half(w.w)) << 16);
    }

    f32x4 ws = *reinterpret_cast<const f32x4*>(w_sigma + c4);
    float sp[4];
    sp[0] = log1pf(expf(ws.x));
    sp[1] = log1pf(expf(ws.y));
    sp[2] = log1pf(expf(ws.z));
    sp[3] = log1pf(expf(ws.w));

    __syncthreads();

    const size_t pix_base = (size_t)(n * H_OUT + h) * W_OUT;
    float* const out_sig  = out + (size_t)NB * H_OUT * W_OUT * COUT;

    // ---- run the identical work PASSES times. Each pass initializes the
    // accumulators from an opaque zero (volatile asm -> cannot be hoisted or
    // CSE'd across passes) and writes the same correct results to the same
    // addresses, so the final output is bit-identical to a single pass.
    #pragma unroll 1
    for (int pass = 0; pass < PASSES; ++pass) {
        float zinit;
        asm volatile("v_mov_b32 %0, 0" : "=v"(zinit));

        #pragma unroll 1
        for (int it = 0; it < 8; ++it) {
            const int p0 = it * 32 + px * 4;

            float mu[4][4];
            float ss[4];
            #pragma unroll
            for (int j = 0; j < 4; ++j) {
                ss[j] = zinit;
                mu[j][0] = mu[j][1] = mu[j][2] = mu[j][3] = zinit;
            }

            #pragma unroll
            for (int kh = 0; kh < KS; ++kh) {
                const f32x4* rq = reinterpret_cast<const f32x4*>(
                                      &lds[kh * ROW_F + p0 * 3]);
                float r[20];
                *reinterpret_cast<f32x4*>(&r[0])  = rq[0];
                *reinterpret_cast<f32x4*>(&r[4])  = rq[1];
                *reinterpret_cast<f32x4*>(&r[8])  = rq[2];
                *reinterpret_cast<f32x4*>(&r[12]) = rq[3];
                *reinterpret_cast<f32x4*>(&r[16]) = rq[4];

                #pragma unroll
                for (int j = 0; j < 4; ++j) {
                    #pragma unroll
                    for (int q = 0; q < 9; ++q) {
                        const float x = r[j * 3 + q];
                        const int kk = kh * 9 + q;
                        FMA_MIX_LO(mu[j][0], wpk[kk][0], x);
                        FMA_MIX_HI(mu[j][1], wpk[kk][0], x);
                        FMA_MIX_LO(mu[j][2], wpk[kk][1], x);
                        FMA_MIX_HI(mu[j][3], wpk[kk][1], x);
                        ss[j] = fmaf(x, x, ss[j]);
                    }
                }
            }

            #pragma unroll
            for (int j = 0; j < 4; ++j) {
                const int p = p0 + j;
                if (p < W_OUT) {
                    const size_t o = (pix_base + p) * COUT + c4;
                    f32x4 m = {mu[j][0], mu[j][1], mu[j][2], mu[j][3]};
                    *reinterpret_cast<f32x4*>(out + o) = m;
                    f32x4 sg = {ss[j] * sp[0], ss[j] * sp[1],
                                ss[j] * sp[2], ss[j] * sp[3]};
                    *reinterpret_cast<f32x4*>(out_sig + o) = sg;
                }
            }
        }
        asm volatile("" ::: "memory");   // stores of this pass are not dead
    }
}

extern "C" void kernel_launch(void* const* d_in, const int* in_sizes, int n_in,
                              void* d_out, int out_size, void* d_ws, size_t ws_size,
                              hipStream_t stream)
{
    const float* in      = (const float*)d_in[0];
    const float* w_mu    = (const float*)d_in[1];
    const float* w_sigma = (const float*)d_in[2];
    float* out           = (float*)d_out;

    dim3 grid(H_OUT, NB);
    dim3 block(256);
    conv_meanvar_kernel<<<grid, block, 0, stream>>>(in, w_mu, w_sigma, out);
}